// Round 6
// baseline (88.492 us; speedup 1.0000x reference)
//
#include <hip/hip_runtime.h>
#include <cstdint>

// CharEmb: per word (B*S=16384): gather 32 char embeddings (E=64) -> x[64][32]
// (raw view of [32 chars][64] buffer), conv1d(F=128,K=3,valid,T=30), bias,
// max over t. Output float32 [16384][128].
//
// MFMA 32x32x16 bf16, M=t, N=f (layouts VERIFIED r1, absmax 0.031):
//   D[t][f] = sum_kk sum_e xT[t+kk][e] * W[f][e][kk]
// xT[c][e] in LDS bf16, row stride 72 (36 dwords); conv shift = LDS addr offset.
// A frag: A[m=lane&31][k=h*8+j]; B frag: B[k][n=lane&31] (prep-packed in ws);
// C/D: col=lane&31, t=(reg&3)+8*(reg>>2)+4*h; t=30,31 (regs 14,15 h=1) masked.
//
// Round 6 = round 5 + SCRATCH FIX. r5 evidence: VGPR_Count=56 (<<~120 design)
// because ch[16] was dynamically indexed (stage_group called with runtime g
// under "#pragma unroll 1") -> LLVM demoted it to scratch; the cid-preload
// optimization became a scratch-load chain. Fix: fully unroll the NGRP loop
// so every ch[] index is compile-time -> array stays in VGPRs.
// Kept from r5 (verified): conflict-free staging map (SQ_LDS_BANK_CONFLICT
// 1.57M -> 0), n=1 tile/wave @ 4 waves/SIMD (r3/r4: fewer waves always lost).

typedef __bf16 bf16x8 __attribute__((ext_vector_type(8)));
typedef float  f32x16 __attribute__((ext_vector_type(16)));

#define NW   16          // words per block; 1024 blocks
#define GW   4           // words staged per barrier group
#define NGRP 4
#define ROWS 34          // rows 0..31 written; 32,33 junk -> feed masked t=30,31
#define RST  72          // row stride in bf16 (36 dwords)
#define BUFE (ROWS * RST)

// Pack conv_w [F=128][E=64][K=3] fp32 -> B-fragment-ordered bf16 in ws:
// pw[((nt*12 + kk*4 + ks)*64 + lane)*8 + j]
//   = w[f=nt*32+(lane&31)][e=ks*16+(lane>>5)*8+j][kk]
__global__ __launch_bounds__(256)
void prep_pack_w(const float* __restrict__ w, __bf16* __restrict__ pw) {
  int i = blockIdx.x * 256 + threadIdx.x;   // 0..24575
  int j    = i & 7;
  int lane = (i >> 3) & 63;
  int ks   = (i >> 9) & 3;
  int t    = i >> 11;        // nt*3 + kk
  int kk   = t % 3;
  int nt   = t / 3;
  int f = nt * 32 + (lane & 31);
  int e = ks * 16 + (lane >> 5) * 8 + j;
  pw[i] = (__bf16)w[f * 192 + e * 3 + kk];
}

__global__ __launch_bounds__(256, 4)
void charcnn_mfma(const int* __restrict__ cid, const float* __restrict__ emb,
                  const float* __restrict__ bias, const __bf16* __restrict__ pw,
                  float* __restrict__ out) {
  // 8 word-buffers (two groups of 4): 8 * 34*72 bf16 = 39168 B -> 4 blocks/CU
  __shared__ __align__(16) __bf16 xT[8][BUFE];

  const int tid  = threadIdx.x;
  const int lane = tid & 63;
  const int wv   = tid >> 6;          // wave id == n-tile (f block of 32)
  const int m    = lane & 31;
  const int h    = lane >> 5;

  // persistent B fragments (weights), 12 frags = 48 VGPRs
  bf16x8 bfrag[12];
  const bf16x8* pwv = (const bf16x8*)pw;
#pragma unroll
  for (int q = 0; q < 12; ++q)        // q = kk*4 + ks
    bfrag[q] = pwv[(wv * 12 + q) * 64 + lane];

  const float vb = bias[wv * 32 + m];

  // staging map (conflict-free, r5-verified): char a = tid&31, slot p = tid>>5
  const int a  = tid & 31;
  const int p  = tid >> 5;
  const int bw = blockIdx.x * NW;

  // Preload this thread's char id for all 16 words. All indices below are
  // compile-time constants (full unroll) -> stays in 16 VGPRs, NOT scratch.
  int ch[NW];
#pragma unroll
  for (int w = 0; w < NW; ++w) ch[w] = cid[(bw + w) * 32 + a];

  // stage 4 words of group g into buffers (g&1)*4 + 0..3:
  // dword[c*36 + a] = pack(emb[ch[a]][c], emb[ch[a]][32+c]), c = 4p..4p+3
  auto stage_group = [&](const int g) {
    const int w0 = g * GW;
#pragma unroll
    for (int i = 0; i < GW; ++i) {
      const float4* er = (const float4*)(emb + ch[w0 + i] * 64);
      float4 lo = er[p];          // dims c = 4p..4p+3
      float4 hi = er[p + 8];      // dims 32+c
      uint32_t* dst = (uint32_t*)(&xT[(g & 1) * 4 + i][0]);
      float lv[4] = {lo.x, lo.y, lo.z, lo.w};
      float hv[4] = {hi.x, hi.y, hi.z, hi.w};
#pragma unroll
      for (int i2 = 0; i2 < 4; ++i2) {
        uint32_t u = ((uint32_t)__builtin_bit_cast(uint16_t, (__bf16)hv[i2]) << 16)
                   |  (uint32_t)__builtin_bit_cast(uint16_t, (__bf16)lv[i2]);
        dst[(4 * p + i2) * 36 + a] = u;   // bank=(16p+4i2+a)%32: conflict-free
      }
    }
  };

  auto compute_word = [&](const int buf, const int w) {
    const __bf16* xb = &xT[buf][0];
    f32x16 acc;
#pragma unroll
    for (int r = 0; r < 16; ++r) acc[r] = 0.0f;

#pragma unroll
    for (int kk = 0; kk < 3; ++kk) {
#pragma unroll
      for (int ks = 0; ks < 4; ++ks) {
        // A[m][k] = xT[m+kk][ks*16 + h*8 + j]
        const bf16x8* ap = (const bf16x8*)(xb + (m + kk) * RST + ks * 16 + h * 8);
        acc = __builtin_amdgcn_mfma_f32_32x32x16_bf16(*ap, bfrag[kk * 4 + ks],
                                                      acc, 0, 0, 0);
      }
    }

    // max over t: t=(reg&3)+8*(reg>>2)+4h; regs 14,15 on h=1 are t=30,31.
    float m0 = acc[0];
#pragma unroll
    for (int r = 1; r <= 13; ++r) m0 = fmaxf(m0, acc[r]);
    float m1 = fmaxf(acc[14], acc[15]);
    float mm = (lane < 32) ? fmaxf(m0, m1) : m0;
    float ot = __shfl_xor(mm, 32, 64);
    float res = fmaxf(mm, ot) + vb;
    if (lane < 32) out[(bw + w) * 128 + wv * 32 + m] = res;
  };

  stage_group(0);
  __syncthreads();
  // FULLY UNROLLED group loop: g is a compile-time constant in every call
  // (keeps ch[] in registers; r5's "#pragma unroll 1" forced runtime g
  // -> scratch spill, VGPR_Count 56).
#pragma unroll
  for (int g = 0; g < NGRP; ++g) {
    if (g + 1 < NGRP) stage_group(g + 1);   // emb loads overlap MFMAs below
#pragma unroll
    for (int i = 0; i < GW; ++i)
      compute_word((g & 1) * 4 + i, g * GW + i);
    __syncthreads();
  }
}

extern "C" void kernel_launch(void* const* d_in, const int* in_sizes, int n_in,
                              void* d_out, int out_size, void* d_ws, size_t ws_size,
                              hipStream_t stream) {
  const int*   cid = (const int*)d_in[0];    // [32*512*32] int32
  const float* emb = (const float*)d_in[1];  // [101*64]  f32
  const float* cw  = (const float*)d_in[2];  // [128*64*3] f32
  const float* cb  = (const float*)d_in[3];  // [128] f32
  float* outp = (float*)d_out;               // [16384*128] f32
  __bf16* pw = (__bf16*)d_ws;                // 24576 bf16 = 48 KB

  hipLaunchKernelGGL(prep_pack_w, dim3(96), dim3(256), 0, stream, cw, pw);
  hipLaunchKernelGGL(charcnn_mfma, dim3(1024), dim3(256), 0, stream,
                     cid, emb, cb, (const __bf16*)pw, outp);
}